// Round 3
// baseline (37.677 us; speedup 1.0000x reference)
//
#include <hip/hip_runtime.h>
#include <hip/hip_cooperative_groups.h>
#include <math.h>

namespace cg = cooperative_groups;

// Problem constants
#define T_LEN   8192
#define D_DIM   128
#define NTHR    128                // 2 waves per block
#define NBLK    64                 // 64 blocks -> 64 CUs, all co-resident
#define OPB     128                // outputs per block
#define NTAP    32                 // rho in [-16,15]; tails underflow (R2: absmax 0.0)
#define GAUSS_C 0.39894228f

// One cooperative kernel: conv + noise -> block min/max -> grid.sync ->
// normalize register-resident accs. ws holds only 128 floats of partials.
__global__ __launch_bounds__(NTHR) void k_coop(
    const float* __restrict__ X, const float* __restrict__ weight,
    const float* __restrict__ noise, const float* __restrict__ sigma,
    float* __restrict__ out, float* __restrict__ ws)
{
    __shared__ float wsc[D_DIM];    // softmax(w)_d * C / sigma_d
    __shared__ float inv2[D_DIM];   // 1/(2 sigma_d^2)
    __shared__ float g2[NTAP];      // combined taps: g2[k] = g(rho = 15-k)
    __shared__ float s[OPB + NTAP]; // spike window, 160 floats
    __shared__ float red[4];

    float* bmin = ws;               // [64]
    float* bmax = ws + NBLK;        // [64]

    const int tid = threadIdx.x;
    const int wv  = tid >> 6;       // wave 0/1
    const int bid = blockIdx.x;
    const int B0  = bid * OPB;
    const int t   = B0 + tid;

    // ---- stage spikes: i in [B0-16, B0+144) ----
    {
        int i = B0 - 16 + tid;
        float x = (i >= 0 && i < T_LEN) ? X[i] : 0.f;
        s[tid] = x > 0.5f ? 1.f : 0.f;
        if (tid < OPB + NTAP - NTHR) {            // 32 extra values
            int i2 = B0 - 16 + NTHR + tid;        // >= 112, only upper bound matters
            float x2 = (i2 < T_LEN) ? X[i2] : 0.f;
            s[NTHR + tid] = x2 > 0.5f ? 1.f : 0.f;
        }
    }
    const float nz = noise[t];

    // ---- softmax(weight), one channel per thread (2 waves) ----
    float w = weight[tid];
    float m = w;
    #pragma unroll
    for (int off = 32; off >= 1; off >>= 1) m = fmaxf(m, __shfl_xor(m, off));
    if ((tid & 63) == 0) red[wv] = m;
    __syncthreads();
    m = fmaxf(red[0], red[1]);
    float e  = __expf(w - m);
    float sm = e;
    #pragma unroll
    for (int off = 32; off >= 1; off >>= 1) sm += __shfl_xor(sm, off);
    if ((tid & 63) == 0) red[2 + wv] = sm;
    __syncthreads();
    sm = red[2] + red[3];
    {
        float sg = sigma[tid];
        wsc[tid]  = (e / sm) * (GAUSS_C / sg);
        inv2[tid] = 1.f / (2.f * sg * sg);
    }
    __syncthreads();

    // ---- combined taps: tap k = tid>>2, channel chunk (tid&3)*32 ----
    {
        int   k  = tid >> 2;
        int   c  = (tid & 3) * 32;
        float rho = (float)(15 - k);
        float r2  = rho * rho;
        float a = 0.f;
        #pragma unroll
        for (int q = 0; q < 8; ++q) {
            float4 wa = *reinterpret_cast<const float4*>(&wsc[c + 4*q]);
            float4 ia = *reinterpret_cast<const float4*>(&inv2[c + 4*q]);
            a = fmaf(wa.x, __expf(-r2 * ia.x), a);
            a = fmaf(wa.y, __expf(-r2 * ia.y), a);
            a = fmaf(wa.z, __expf(-r2 * ia.z), a);
            a = fmaf(wa.w, __expf(-r2 * ia.w), a);
        }
        a += __shfl_xor(a, 1);
        a += __shfl_xor(a, 2);
        if ((tid & 3) == 0) g2[k] = a;
    }
    __syncthreads();

    // ---- 32-tap conv: psedu[t] = sum_k s[tid+k] * g2[k] + noise[t] ----
    float g2r[NTAP];
    #pragma unroll
    for (int q = 0; q < 8; ++q) {
        float4 v = *reinterpret_cast<const float4*>(&g2[4*q]);
        g2r[4*q+0] = v.x; g2r[4*q+1] = v.y; g2r[4*q+2] = v.z; g2r[4*q+3] = v.w;
    }
    float a = 0.f;
    #pragma unroll
    for (int k = 0; k < NTAP; ++k)
        a = fmaf(s[tid + k], g2r[k], a);
    const float acc = a + nz;

    // ---- block min/max -> ws partials ----
    float mn = acc, mx = acc;
    #pragma unroll
    for (int off = 32; off >= 1; off >>= 1) {
        mn = fminf(mn, __shfl_xor(mn, off));
        mx = fmaxf(mx, __shfl_xor(mx, off));
    }
    __syncthreads();                 // red[] reuse safe
    if ((tid & 63) == 0) { red[wv] = mn; red[2 + wv] = mx; }
    __syncthreads();
    if (tid == 0) {
        bmin[bid] = fminf(red[0], red[1]);
        bmax[bid] = fmaxf(red[2], red[3]);
    }

    // ---- grid-wide barrier (includes device-scope memory fence) ----
    cg::this_grid().sync();

    // ---- global min/max from 64 partials; each wave reduces independently ----
    float mnv = bmin[tid & 63];
    float mxv = bmax[tid & 63];
    #pragma unroll
    for (int off = 32; off >= 1; off >>= 1) {
        mnv = fminf(mnv, __shfl_xor(mnv, off));
        mxv = fmaxf(mxv, __shfl_xor(mxv, off));
    }
    out[t] = (acc - mnv) * (1.f / (mxv - mnv));
}

extern "C" void kernel_launch(void* const* d_in, const int* in_sizes, int n_in,
                              void* d_out, int out_size, void* d_ws, size_t ws_size,
                              hipStream_t stream) {
    const float* X      = (const float*)d_in[0];   // (1, 8192)
    const float* weight = (const float*)d_in[1];   // (1, 128)
    const float* noise  = (const float*)d_in[2];   // (1, 8192)
    const float* sigma  = (const float*)d_in[3];   // (128,)
    float* out = (float*)d_out;                    // (1, 8192) float32
    float* ws  = (float*)d_ws;                     // 128 floats of partials

    void* args[] = { (void*)&X, (void*)&weight, (void*)&noise,
                     (void*)&sigma, (void*)&out, (void*)&ws };
    hipLaunchCooperativeKernel(reinterpret_cast<void*>(k_coop),
                               dim3(NBLK), dim3(NTHR), args, 0, stream);
}

// Round 4
// 11.041 us; speedup vs baseline: 3.4123x; 3.4123x over previous
//
#include <hip/hip_runtime.h>
#include <math.h>

// Problem constants
#define T_LEN   8192
#define D_DIM   128
#define NTHR    128                // 2 waves per block
#define NBLK    64                 // 8192 / 128 outputs per block
#define OPB     128
#define NTAP    32                 // rho in [-16,15]; tails underflow f32 (R2/R3: absmax 0.0)
#define GAUSS_C 0.39894228f

// ws layout: float2 pmm[128] (per-wave {min,max}), then float psedu[T_LEN]

__global__ __launch_bounds__(NTHR) void k_conv(
    const float* __restrict__ X, const float* __restrict__ weight,
    const float* __restrict__ noise, const float* __restrict__ sigma,
    float* __restrict__ psedu, float2* __restrict__ pmm)
{
    __shared__ float wsc[D_DIM];    // e_d * C / sigma_d  (UNNORMALIZED; /S folded into epilogue)
    __shared__ float inv2[D_DIM];   // 1/(2 sigma_d^2)
    __shared__ float g2[NTAP];      // combined (unnormalized) taps: g2[k] = g(rho = 15-k)
    __shared__ float s[OPB + NTAP]; // spike window
    __shared__ float redS[2];       // per-wave exp-sum partials

    const int tid = threadIdx.x;
    const int wv  = tid >> 6;
    const int bid = blockIdx.x;
    const int B0  = bid * OPB;
    const int t   = B0 + tid;

    // ---- issue all global loads up front (branchless, clamped) ----
    const int   i   = B0 - 16 + tid;            // i < T_LEN always (max 8175)
    const float x   = X[max(i, 0)];
    const int   i2  = i + NTHR;                 // used by tid < 32
    const float x2  = X[min(i2, T_LEN - 1)];
    const float nz  = noise[t];
    const float w   = weight[tid];
    const float sg  = sigma[tid];

    s[tid] = (x > 0.5f && i >= 0) ? 1.f : 0.f;
    if (tid < OPB + NTAP - NTHR)
        s[NTHR + tid] = (x2 > 0.5f && i2 < T_LEN) ? 1.f : 0.f;

    // ---- unnormalized softmax weights; S reduced concurrently ----
    // (softmax is shift-invariant; weights are O(1) so no max-subtract needed)
    const float e = __expf(w);
    wsc[tid]  = e * (GAUSS_C / sg);
    inv2[tid] = 1.f / (2.f * sg * sg);
    float S = e;
    #pragma unroll
    for (int off = 32; off >= 1; off >>= 1) S += __shfl_xor(S, off);
    if ((tid & 63) == 0) redS[wv] = S;
    __syncthreads();                             // covers wsc/inv2/s/redS
    const float invS = 1.f / (redS[0] + redS[1]);

    // ---- combined taps: tap k = tid>>2, 32 channels per lane-group ----
    {
        const int   k   = tid >> 2;
        const int   c   = (tid & 3) * 32;
        const float rho = (float)(15 - k);
        const float r2  = rho * rho;
        float a = 0.f;
        #pragma unroll
        for (int q = 0; q < 8; ++q) {
            float4 wa = *reinterpret_cast<const float4*>(&wsc[c + 4*q]);
            float4 ia = *reinterpret_cast<const float4*>(&inv2[c + 4*q]);
            a = fmaf(wa.x, __expf(-r2 * ia.x), a);
            a = fmaf(wa.y, __expf(-r2 * ia.y), a);
            a = fmaf(wa.z, __expf(-r2 * ia.z), a);
            a = fmaf(wa.w, __expf(-r2 * ia.w), a);
        }
        a += __shfl_xor(a, 1);
        a += __shfl_xor(a, 2);
        if ((tid & 3) == 0) g2[k] = a;
    }
    __syncthreads();

    // ---- 32-tap conv: psedu[t] = (sum_k s[tid+k] * g2[k]) / S + noise[t] ----
    float g2r[NTAP];
    #pragma unroll
    for (int q = 0; q < 8; ++q) {
        float4 v = *reinterpret_cast<const float4*>(&g2[4*q]);
        g2r[4*q+0] = v.x; g2r[4*q+1] = v.y; g2r[4*q+2] = v.z; g2r[4*q+3] = v.w;
    }
    float a = 0.f;
    #pragma unroll
    for (int k = 0; k < NTAP; ++k)
        a = fmaf(s[tid + k], g2r[k], a);
    const float acc = fmaf(a, invS, nz);
    psedu[t] = acc;

    // ---- per-wave min/max straight to global (no cross-wave combine) ----
    float mn = acc, mx = acc;
    #pragma unroll
    for (int off = 32; off >= 1; off >>= 1) {
        mn = fminf(mn, __shfl_xor(mn, off));
        mx = fmaxf(mx, __shfl_xor(mx, off));
    }
    if ((tid & 63) == 0) pmm[bid * 2 + wv] = make_float2(mn, mx);
}

__global__ __launch_bounds__(NTHR) void k_norm(
    const float* __restrict__ psedu, const float2* __restrict__ pmm,
    float* __restrict__ out)
{
    const int tid  = threadIdx.x;
    const int lane = tid & 63;
    const int t    = blockIdx.x * NTHR + tid;

    const float  p = psedu[t];                  // issues in parallel with pmm loads
    const float2 a = pmm[lane];
    const float2 b = pmm[lane + 64];
    float mn = fminf(a.x, b.x);
    float mx = fmaxf(a.y, b.y);
    #pragma unroll
    for (int off = 32; off >= 1; off >>= 1) {
        mn = fminf(mn, __shfl_xor(mn, off));
        mx = fmaxf(mx, __shfl_xor(mx, off));
    }
    out[t] = (p - mn) * (1.f / (mx - mn));
}

extern "C" void kernel_launch(void* const* d_in, const int* in_sizes, int n_in,
                              void* d_out, int out_size, void* d_ws, size_t ws_size,
                              hipStream_t stream) {
    const float* X      = (const float*)d_in[0];   // (1, 8192)
    const float* weight = (const float*)d_in[1];   // (1, 128)
    const float* noise  = (const float*)d_in[2];   // (1, 8192)
    const float* sigma  = (const float*)d_in[3];   // (128,)
    float* out = (float*)d_out;                    // (1, 8192) float32

    float2* pmm   = (float2*)d_ws;                 // 128 float2
    float*  psedu = (float*)d_ws + 256;            // 8192 floats

    k_conv<<<NBLK, NTHR, 0, stream>>>(X, weight, noise, sigma, psedu, pmm);
    k_norm<<<NBLK, NTHR, 0, stream>>>(psedu, pmm, out);
}